// Round 7
// baseline (252.193 us; speedup 1.0000x reference)
//
#include <hip/hip_runtime.h>
#include <cstddef>

#define BB 4
#define SS 2048
#define DMOD 32
#define AEL (BB*SS*DMOD)            // 262144 floats per projection array
#define WS_PROJ 16                  // reserved header (unused now)
#define MB0 (WS_PROJ + 8*AEL)       // pmask (u64 x MWORDS) then nmask
#define MWORDS (BB*32*SS)           // 262144 u64 per mask
#define PART0 (MB0 + 4*MWORDS)      // float offset of partials
#define PSLOT (36*8192)             // floats per (pn, chunk) partial slot
#define TINY 1e-30f

__device__ __forceinline__ float fexp2(float x) {
#if defined(__has_builtin)
#if __has_builtin(__builtin_amdgcn_exp2f)
    return __builtin_amdgcn_exp2f(x);
#else
    return exp2f(x);
#endif
#else
    return exp2f(x);
#endif
}

// ---------- kernel 1: all 8 projections ----------
// mats: 0 q_o (raw), 1 k_o, 2 q_p (log2e/sqrt8), 3 k_p, 4 v_p,
//       5 q_n (log2e/sqrt8), 6 k_n, 7 v_n
__global__ __launch_bounds__(256) void k1_proj(
    const float* __restrict__ feat,
    const float* __restrict__ qw, const float* __restrict__ qb,
    const float* __restrict__ kw, const float* __restrict__ kb,
    const float* __restrict__ paw, const float* __restrict__ pab,
    const float* __restrict__ naw, const float* __restrict__ nab,
    float* __restrict__ wsf) {
    int g = blockIdx.x * 256 + threadIdx.x;
    int d4  = g & 7;
    int mat = (g >> 3) & 7;
    int row = g >> 6;
    const float* W; const float* Bv; float sc = 1.f;
    switch (mat) {
        case 0: W = qw;        Bv = qb;       break;
        case 1: W = kw;        Bv = kb;       break;
        case 2: W = paw;       Bv = pab;      sc = 0.5101370246954918f; break;
        case 3: W = paw+1024;  Bv = pab+32;   break;
        case 4: W = paw+2048;  Bv = pab+64;   break;
        case 5: W = naw;       Bv = nab;      sc = 0.5101370246954918f; break;
        case 6: W = naw+1024;  Bv = nab+32;   break;
        default:W = naw+2048;  Bv = nab+64;   break;
    }
    const float* fr = feat + row * DMOD;
    int o0 = d4 * 4;
    float acc[4];
    #pragma unroll
    for (int i = 0; i < 4; i++) acc[i] = Bv[o0+i];
    #pragma unroll
    for (int d = 0; d < DMOD; d++) {
        float fv = fr[d];
        #pragma unroll
        for (int i = 0; i < 4; i++) acc[i] += fv * W[(o0+i)*DMOD + d];
    }
    #pragma unroll
    for (int i = 0; i < 4; i++) acc[i] *= sc;
    float4 r = make_float4(acc[0], acc[1], acc[2], acc[3]);
    *(float4*)(wsf + WS_PROJ + (size_t)mat*AEL + (size_t)row*DMOD + o0) = r;
}

// ---------- kernel A: fused-score sign bits -> packed p/n masks ----------
// grid (jt=8, rt=16, b=4), block 256 = 4 waves x 64 lanes (lane = j offset)
// c[4]/cb computed inline from conv weights (uniform scalar math).
__global__ __launch_bounds__(256) void kA_mask(
    const float* __restrict__ dmask, float* __restrict__ wsf,
    const float* __restrict__ f1w, const float* __restrict__ f1b,
    const float* __restrict__ f2w, const float* __restrict__ f2b,
    const float* __restrict__ f3w, const float* __restrict__ f3b) {
    int tid = threadIdx.x;
    int w = tid >> 6, lane = tid & 63;
    int jt = blockIdx.x, rt = blockIdx.y, b = blockIdx.z;
    int jg = jt * 256 + w * 64 + lane;          // batch-local j

    // collapse conv stack: c_h = (1/sqrt8) * sum_a f3[a] sum_b f2[a,b] f1[b,h]
    float cc[4];
    #pragma unroll
    for (int h = 0; h < 4; h++) {
        float s = 0.f;
        #pragma unroll
        for (int a = 0; a < 4; a++) {
            float t = 0.f;
            #pragma unroll
            for (int bb = 0; bb < 8; bb++) t += f2w[a*8+bb] * f1w[bb*4+h];
            s += f3w[a] * t;
        }
        cc[h] = s * 0.35355339059327373f;
    }
    float cbv = f3b[0];
    #pragma unroll
    for (int a = 0; a < 4; a++) {
        float t = f2b[a];
        #pragma unroll
        for (int bb = 0; bb < 8; bb++) t += f2w[a*8+bb] * f1b[bb];
        cbv += f3w[a] * t;
    }

    const float* KOb = wsf + WS_PROJ + 1*(size_t)AEL + ((size_t)b*SS + jg) * DMOD;
    float ko[32];
    #pragma unroll
    for (int i = 0; i < 8; i++) {
        float4 v = *(const float4*)(KOb + 4*i);
        ko[4*i] = v.x; ko[4*i+1] = v.y; ko[4*i+2] = v.z; ko[4*i+3] = v.w;
    }
    const float* QOb = wsf + WS_PROJ + 0*(size_t)AEL + (size_t)b*SS*DMOD;
    unsigned long long* pm = (unsigned long long*)(wsf + MB0);
    unsigned long long* nm = pm + MWORDS;
    int j64 = jt * 4 + w;
    size_t mbase = ((size_t)b * 32 + j64) * SS;
    #pragma unroll 2
    for (int r = 0; r < 128; r++) {
        int row = rt * 128 + r;
        const float* qr = QOb + (size_t)row * DMOD;
        float fa = 0.f, fb = 0.f, fc = 0.f, fd = 0.f;   // per-head raw dots
        #pragma unroll
        for (int d = 0; d < 8; d++) {
            fa += qr[d]      * ko[d];
            fb += qr[8 + d]  * ko[8 + d];
            fc += qr[16 + d] * ko[16 + d];
            fd += qr[24 + d] * ko[24 + d];
        }
        float fused = cbv + cc[0]*fa + cc[1]*fb + cc[2]*fc + cc[3]*fd;
        float dm = dmask[((size_t)b * SS + row) * SS + jg];
        bool act = (dm != 0.0f);
        unsigned long long bp = __ballot(act && (fused > 0.0f));
        unsigned long long bn = __ballot(act && !(fused > 0.0f));
        if (lane == 0) {
            pm[mbase + row] = bp;
            nm[mbase + row] = bn;
        }
    }
}

// ---------- kernel B: masked attention (p or n), split-K ----------
// grid (jc=NCH, rt=8, z=8: b=z>>1, pn=z&1), block 256 = 256 rows (all 4 heads)
__global__ __launch_bounds__(256) void kB_attn(
    const float* __restrict__ wsf_c, float* __restrict__ wsf, int CJ) {
    int tid = threadIdx.x;
    int jc = blockIdx.x, rt = blockIdx.y;
    int b = blockIdx.z >> 1, pn = blockIdx.z & 1;
    int row = rt * 256 + tid;
    size_t grow = (size_t)b * SS + row;

    int qm = pn ? 5 : 2, km = pn ? 6 : 3, vm = pn ? 7 : 4;
    const float* Qb = wsf_c + WS_PROJ + (size_t)qm*AEL + grow*DMOD;
    const float* Kb = wsf_c + WS_PROJ + (size_t)km*AEL + (size_t)b*SS*DMOD;
    const float* Vb = wsf_c + WS_PROJ + (size_t)vm*AEL + (size_t)b*SS*DMOD;
    const unsigned long long* msk =
        (const unsigned long long*)(wsf_c + MB0) + (size_t)pn * MWORDS;

    float ql[32];
    #pragma unroll
    for (int i = 0; i < 8; i++) {
        float4 v = *(const float4*)(Qb + 4*i);
        ql[4*i] = v.x; ql[4*i+1] = v.y; ql[4*i+2] = v.z; ql[4*i+3] = v.w;
    }
    float a[32];
    #pragma unroll
    for (int i = 0; i < 32; i++) a[i] = 0.f;
    float l[4] = {0.f, 0.f, 0.f, 0.f};

    int jA0 = jc * CJ;
    for (int j0 = 0; j0 < CJ; j0 += 64) {
        int jA = jA0 + j0;
        unsigned long long mw = msk[((size_t)b * 32 + (jA >> 6)) * SS + row];
        #pragma unroll 2
        for (int jj = 0; jj < 64; jj++) {
            const float* kp = Kb + ((size_t)(jA + jj) << 5);
            const float* vp = Vb + ((size_t)(jA + jj) << 5);
            float kv[32];
            #pragma unroll
            for (int i = 0; i < 8; i++)
                *(float4*)(kv + 4*i) = *(const float4*)(kp + 4*i);
            float s0 = 0.f, s1 = 0.f, s2 = 0.f, s3 = 0.f;
            #pragma unroll
            for (int e = 0; e < 8; e++) {
                s0 += ql[e]      * kv[e];
                s1 += ql[8 + e]  * kv[8 + e];
                s2 += ql[16 + e] * kv[16 + e];
                s3 += ql[24 + e] * kv[24 + e];
            }
            bool bit = ((unsigned)(mw >> jj) & 1u) != 0u;
            float w0 = bit ? fexp2(s0) : TINY;
            float w1 = bit ? fexp2(s1) : TINY;
            float w2 = bit ? fexp2(s2) : TINY;
            float w3 = bit ? fexp2(s3) : TINY;
            l[0] += w0; l[1] += w1; l[2] += w2; l[3] += w3;
            float vv[32];
            #pragma unroll
            for (int i = 0; i < 8; i++)
                *(float4*)(vv + 4*i) = *(const float4*)(vp + 4*i);
            #pragma unroll
            for (int e = 0; e < 8; e++) {
                a[e]      += w0 * vv[e];
                a[8 + e]  += w1 * vv[8 + e];
                a[16 + e] += w2 * vv[16 + e];
                a[24 + e] += w3 * vv[24 + e];
            }
        }
    }
    // partial slot: [pn*NCH + jc][36][8192]; k = 0..3 l[h], 4..35 a[h*8+e]
    float* pb = wsf + PART0 + (size_t)(pn * gridDim.x + jc) * PSLOT + grow;
    #pragma unroll
    for (int h = 0; h < 4; h++)
        pb[(size_t)h * 8192] = l[h];
    #pragma unroll
    for (int e = 0; e < 32; e++)
        pb[(size_t)(4 + e) * 8192] = a[e];
}

// ---------- kernel 3a: reduce split-K partials into chunk 0 (per pn) ----------
__global__ __launch_bounds__(256) void k3a_red(float* __restrict__ part, int NCH) {
    int idx = blockIdx.x * 256 + threadIdx.x;   // 147456 float4 slots (2*36*8192/4)
    size_t e = (size_t)idx * 4;
    int pn = (int)(e / PSLOT);
    size_t off = e - (size_t)pn * PSLOT;
    float* base = part + (size_t)pn * NCH * PSLOT + off;
    float4 s = *(const float4*)base;
    for (int c = 1; c < NCH; c++) {
        float4 v = *(const float4*)(base + (size_t)c * PSLOT);
        s.x += v.x; s.y += v.y; s.z += v.z; s.w += v.w;
    }
    *(float4*)base = s;
}

// ---------- kernel 3b: normalize + out-proj + gate (8 rows/block, 32 lanes/row) ----------
__global__ __launch_bounds__(256) void k3b_fin(
    const float* __restrict__ part, int NCH,
    const float* __restrict__ paw, const float* __restrict__ pab,
    const float* __restrict__ naw, const float* __restrict__ nab,
    const float* __restrict__ vpw, const float* __restrict__ vpb,
    const float* __restrict__ vnw, const float* __restrict__ vnb,
    const float* __restrict__ gpw, const float* __restrict__ gpb,
    float* __restrict__ out) {
    __shared__ float sums[8][72];
    __shared__ float Pl[8][64];    // [0..31]=Pp, [32..63]=Pn
    __shared__ float pnv[8][64];   // [0..31]=p,  [32..63]=n
    int tid = threadIdx.x;
    int r = tid >> 5, o = tid & 31;
    int row = blockIdx.x * 8 + r;
    const float* b0 = part + row;                        // pn=0, chunk 0
    const float* b1 = part + (size_t)NCH * PSLOT + row;  // pn=1, chunk 0
    for (int v = o; v < 72; v += 32) {
        int pn = v >= 36;
        int k = v - 36 * pn;
        sums[r][v] = (pn ? b1 : b0)[(size_t)k * 8192];
    }
    __syncthreads();
    // Pp[o] = a_p[o]/l_p[o>>3]; layout: k 0..3 = l, 4..35 = a
    Pl[r][o]      = sums[r][4 + o]  / sums[r][o >> 3];
    Pl[r][32 + o] = sums[r][40 + o] / sums[r][36 + (o >> 3)];
    __syncthreads();
    const float* pw3 = paw + 3*1024; const float* pb3 = pab + 3*32;
    const float* nw3 = naw + 3*1024; const float* nb3 = nab + 3*32;
    float pv = pb3[o], nv = nb3[o];
    #pragma unroll
    for (int d = 0; d < 32; d++) {
        pv += Pl[r][d]      * pw3[o*32 + d];
        nv += Pl[r][32 + d] * nw3[o*32 + d];
    }
    pnv[r][o] = pv; pnv[r][32 + o] = nv;
    __syncthreads();
    float vp = vpb[o], vn = vnb[o], ep = gpb[o], en = gpb[o];
    #pragma unroll
    for (int d = 0; d < 32; d++) {
        float pd = pnv[r][d], nd = pnv[r][32 + d];
        vp += pd * vpw[o*32 + d];
        vn += nd * vnw[o*32 + d];
        ep += pd * gpw[o*32 + d];
        en += nd * gpw[o*32 + d];
    }
    float g = 1.0f / (1.0f + __expf(en - ep));
    out[(size_t)row * 32 + o] = vp * g + vn * (1.0f - g);
}

extern "C" void kernel_launch(void* const* d_in, const int* in_sizes, int n_in,
                              void* d_out, int out_size, void* d_ws, size_t ws_size,
                              hipStream_t stream) {
    const float* feat  = (const float*)d_in[0];
    const float* dmask = (const float*)d_in[1];
    const float* qw  = (const float*)d_in[2];  const float* qb  = (const float*)d_in[3];
    const float* kw  = (const float*)d_in[4];  const float* kb  = (const float*)d_in[5];
    const float* f1w = (const float*)d_in[6];  const float* f1b = (const float*)d_in[7];
    const float* f2w = (const float*)d_in[8];  const float* f2b = (const float*)d_in[9];
    const float* f3w = (const float*)d_in[10]; const float* f3b = (const float*)d_in[11];
    const float* paw = (const float*)d_in[12]; const float* pab = (const float*)d_in[13];
    const float* naw = (const float*)d_in[14]; const float* nab = (const float*)d_in[15];
    const float* vpw = (const float*)d_in[16]; const float* vpb = (const float*)d_in[17];
    const float* vnw = (const float*)d_in[18]; const float* vnb = (const float*)d_in[19];
    const float* gpw = (const float*)d_in[20]; const float* gpb = (const float*)d_in[21];
    float* wsf = (float*)d_ws;
    float* out = (float*)d_out;

    // pick split-K chunk count that fits ws (per chunk: 2 pn x 36*8192 floats)
    size_t avail = ws_size / 4;
    int nch = 1;
    if (avail > (size_t)PART0) {
        size_t per = (size_t)2 * PSLOT;
        size_t m = (avail - PART0) / per;
        nch = (m >= 32) ? 32 : (m >= 16) ? 16 : (m >= 8) ? 8 : (m >= 4) ? 4 :
              (m >= 2) ? 2 : 1;
    }
    int cj = SS / nch;
    float* part = wsf + PART0;

    hipLaunchKernelGGL(k1_proj, dim3(2048), dim3(256), 0, stream,
                       feat, qw, qb, kw, kb, paw, pab, naw, nab, wsf);
    hipLaunchKernelGGL(kA_mask, dim3(8, 16, BB), dim3(256), 0, stream,
                       dmask, wsf, f1w, f1b, f2w, f2b, f3w, f3b);
    hipLaunchKernelGGL(kB_attn, dim3(nch, 8, BB*2), dim3(256), 0, stream,
                       wsf, wsf, cj);
    if (nch > 1)
        hipLaunchKernelGGL(k3a_red, dim3(576), dim3(256), 0, stream, part, nch);
    hipLaunchKernelGGL(k3b_fin, dim3(1024), dim3(256), 0, stream,
                       part, nch, paw, pab, naw, nab, vpw, vpb, vnw, vnb, gpw, gpb,
                       out);
}

// Round 8
// 211.217 us; speedup vs baseline: 1.1940x; 1.1940x over previous
//
#include <hip/hip_runtime.h>
#include <cstddef>

#define BB 4
#define SS 2048
#define DMOD 32
#define AEL (BB*SS*DMOD)            // 262144 floats per projection array
#define WS_PROJ 16                  // reserved header
#define MB0 (WS_PROJ + 8*AEL)       // pmask (u64 x MWORDS) then nmask
#define MWORDS (BB*32*SS)           // 262144 u64 per mask
#define PART0 (MB0 + 4*MWORDS)      // float offset of partials
#define PSLOT (36*8192)             // floats per (pn, chunk) partial slot
#define TINY 1e-30f

__device__ __forceinline__ float fexp2(float x) {
#if defined(__has_builtin)
#if __has_builtin(__builtin_amdgcn_exp2f)
    return __builtin_amdgcn_exp2f(x);
#else
    return exp2f(x);
#endif
#else
    return exp2f(x);
#endif
}

// ---------- kernel 1: all 8 projections ----------
// mats: 0 q_o (raw), 1 k_o, 2 q_p (log2e/sqrt8), 3 k_p, 4 v_p,
//       5 q_n (log2e/sqrt8), 6 k_n, 7 v_n
__global__ __launch_bounds__(256) void k1_proj(
    const float* __restrict__ feat,
    const float* __restrict__ qw, const float* __restrict__ qb,
    const float* __restrict__ kw, const float* __restrict__ kb,
    const float* __restrict__ paw, const float* __restrict__ pab,
    const float* __restrict__ naw, const float* __restrict__ nab,
    float* __restrict__ wsf) {
    int g = blockIdx.x * 256 + threadIdx.x;
    int d4  = g & 7;
    int mat = (g >> 3) & 7;
    int row = g >> 6;
    const float* W; const float* Bv; float sc = 1.f;
    switch (mat) {
        case 0: W = qw;        Bv = qb;       break;
        case 1: W = kw;        Bv = kb;       break;
        case 2: W = paw;       Bv = pab;      sc = 0.5101370246954918f; break;
        case 3: W = paw+1024;  Bv = pab+32;   break;
        case 4: W = paw+2048;  Bv = pab+64;   break;
        case 5: W = naw;       Bv = nab;      sc = 0.5101370246954918f; break;
        case 6: W = naw+1024;  Bv = nab+32;   break;
        default:W = naw+2048;  Bv = nab+64;   break;
    }
    const float* fr = feat + row * DMOD;
    int o0 = d4 * 4;
    float acc[4];
    #pragma unroll
    for (int i = 0; i < 4; i++) acc[i] = Bv[o0+i];
    #pragma unroll
    for (int d = 0; d < DMOD; d++) {
        float fv = fr[d];
        #pragma unroll
        for (int i = 0; i < 4; i++) acc[i] += fv * W[(o0+i)*DMOD + d];
    }
    #pragma unroll
    for (int i = 0; i < 4; i++) acc[i] *= sc;
    float4 r = make_float4(acc[0], acc[1], acc[2], acc[3]);
    *(float4*)(wsf + WS_PROJ + (size_t)mat*AEL + (size_t)row*DMOD + o0) = r;
}

// ---------- kernel A: fused-score sign bits -> packed p/n masks ----------
// grid (jt=8, rt=32, b=4), block 256 = 4 waves x 64 lanes (lane = j offset)
__global__ __launch_bounds__(256) void kA_mask(
    const float* __restrict__ dmask, float* __restrict__ wsf,
    const float* __restrict__ f1w, const float* __restrict__ f1b,
    const float* __restrict__ f2w, const float* __restrict__ f2b,
    const float* __restrict__ f3w, const float* __restrict__ f3b) {
    int tid = threadIdx.x;
    int w = tid >> 6, lane = tid & 63;
    int jt = blockIdx.x, rt = blockIdx.y, b = blockIdx.z;
    int jg = jt * 256 + w * 64 + lane;          // batch-local j

    // collapse conv stack: c_h = (1/sqrt8) * sum_a f3[a] sum_b f2[a,b] f1[b,h]
    float cc[4];
    #pragma unroll
    for (int h = 0; h < 4; h++) {
        float s = 0.f;
        #pragma unroll
        for (int a = 0; a < 4; a++) {
            float t = 0.f;
            #pragma unroll
            for (int bb = 0; bb < 8; bb++) t += f2w[a*8+bb] * f1w[bb*4+h];
            s += f3w[a] * t;
        }
        cc[h] = s * 0.35355339059327373f;
    }
    float cbv = f3b[0];
    #pragma unroll
    for (int a = 0; a < 4; a++) {
        float t = f2b[a];
        #pragma unroll
        for (int bb = 0; bb < 8; bb++) t += f2w[a*8+bb] * f1b[bb];
        cbv += f3w[a] * t;
    }

    const float* KOb = wsf + WS_PROJ + 1*(size_t)AEL + ((size_t)b*SS + jg) * DMOD;
    float ko[32];
    #pragma unroll
    for (int i = 0; i < 8; i++) {
        float4 v = *(const float4*)(KOb + 4*i);
        ko[4*i] = v.x; ko[4*i+1] = v.y; ko[4*i+2] = v.z; ko[4*i+3] = v.w;
    }
    const float* QOb = wsf + WS_PROJ + 0*(size_t)AEL + (size_t)b*SS*DMOD;
    unsigned long long* pm = (unsigned long long*)(wsf + MB0);
    unsigned long long* nm = pm + MWORDS;
    int j64 = jt * 4 + w;
    size_t mbase = ((size_t)b * 32 + j64) * SS;
    #pragma unroll 4
    for (int r = 0; r < 64; r++) {
        int row = rt * 64 + r;
        const float* qr = QOb + (size_t)row * DMOD;
        float dm = dmask[((size_t)b * SS + row) * SS + jg];
        float fa = 0.f, fb = 0.f, fc = 0.f, fd = 0.f;   // per-head raw dots
        #pragma unroll
        for (int d = 0; d < 8; d++) {
            fa += qr[d]      * ko[d];
            fb += qr[8 + d]  * ko[8 + d];
            fc += qr[16 + d] * ko[16 + d];
            fd += qr[24 + d] * ko[24 + d];
        }
        float fused = cbv + cc[0]*fa + cc[1]*fb + cc[2]*fc + cc[3]*fd;
        bool act = (dm != 0.0f);
        unsigned long long bp = __ballot(act && (fused > 0.0f));
        unsigned long long bn = __ballot(act && !(fused > 0.0f));
        if (lane == 0) {
            pm[mbase + row] = bp;
            nm[mbase + row] = bn;
        }
    }
}

// ---------- kernel B: masked attention (p or n), split-K, LDS-staged K/V ----------
// grid (jc=NCH, rt=8, z=8: b=z>>1, pn=z&1), block 256 = 256 rows (all 4 heads)
__global__ __launch_bounds__(256) void kB_attn(
    const float* __restrict__ wsf_c, float* __restrict__ wsf, int CJ) {
    __shared__ float kls[64 * 32];   // 8 KB: K rows for current 64-j window
    __shared__ float vls[64 * 32];   // 8 KB: V rows
    int tid = threadIdx.x;
    int jc = blockIdx.x, rt = blockIdx.y;
    int b = blockIdx.z >> 1, pn = blockIdx.z & 1;
    int row = rt * 256 + tid;
    size_t grow = (size_t)b * SS + row;

    int qm = pn ? 5 : 2, km = pn ? 6 : 3, vm = pn ? 7 : 4;
    const float* Qb = wsf_c + WS_PROJ + (size_t)qm*AEL + grow*DMOD;
    const float* Kb = wsf_c + WS_PROJ + (size_t)km*AEL + (size_t)b*SS*DMOD;
    const float* Vb = wsf_c + WS_PROJ + (size_t)vm*AEL + (size_t)b*SS*DMOD;
    const unsigned long long* msk =
        (const unsigned long long*)(wsf_c + MB0) + (size_t)pn * MWORDS;

    float ql[32];
    #pragma unroll
    for (int i = 0; i < 8; i++) {
        float4 v = *(const float4*)(Qb + 4*i);
        ql[4*i] = v.x; ql[4*i+1] = v.y; ql[4*i+2] = v.z; ql[4*i+3] = v.w;
    }
    float a[32];
    #pragma unroll
    for (int i = 0; i < 32; i++) a[i] = 0.f;
    float l[4] = {0.f, 0.f, 0.f, 0.f};

    int jA0 = jc * CJ;
    for (int j0 = 0; j0 < CJ; j0 += 64) {
        int jA = jA0 + j0;
        // cooperative stage: 64 K-rows + 64 V-rows (2 x 8 KB, fully coalesced)
        __syncthreads();
        {
            const float4* Ksrc = (const float4*)(Kb + ((size_t)jA << 5));
            const float4* Vsrc = (const float4*)(Vb + ((size_t)jA << 5));
            float4* kd = (float4*)kls;
            float4* vd = (float4*)vls;
            kd[tid]       = Ksrc[tid];
            kd[tid + 256] = Ksrc[tid + 256];
            vd[tid]       = Vsrc[tid];
            vd[tid + 256] = Vsrc[tid + 256];
        }
        __syncthreads();
        unsigned long long mw = msk[((size_t)b * 32 + (jA >> 6)) * SS + row];
        #pragma unroll 2
        for (int jj = 0; jj < 64; jj++) {
            const float* kr = kls + (jj << 5);
            const float* vr = vls + (jj << 5);
            float kv[32];
            #pragma unroll
            for (int i = 0; i < 8; i++)
                *(float4*)(kv + 4*i) = *(const float4*)(kr + 4*i);
            float s0 = 0.f, s1 = 0.f, s2 = 0.f, s3 = 0.f;
            #pragma unroll
            for (int e = 0; e < 8; e++) {
                s0 += ql[e]      * kv[e];
                s1 += ql[8 + e]  * kv[8 + e];
                s2 += ql[16 + e] * kv[16 + e];
                s3 += ql[24 + e] * kv[24 + e];
            }
            bool bit = ((unsigned)(mw >> jj) & 1u) != 0u;
            float w0 = bit ? fexp2(s0) : TINY;
            float w1 = bit ? fexp2(s1) : TINY;
            float w2 = bit ? fexp2(s2) : TINY;
            float w3 = bit ? fexp2(s3) : TINY;
            l[0] += w0; l[1] += w1; l[2] += w2; l[3] += w3;
            float vv[32];
            #pragma unroll
            for (int i = 0; i < 8; i++)
                *(float4*)(vv + 4*i) = *(const float4*)(vr + 4*i);
            #pragma unroll
            for (int e = 0; e < 8; e++) {
                a[e]      += w0 * vv[e];
                a[8 + e]  += w1 * vv[8 + e];
                a[16 + e] += w2 * vv[16 + e];
                a[24 + e] += w3 * vv[24 + e];
            }
        }
    }
    // partial slot: [pn*NCH + jc][36][8192]; k = 0..3 l[h], 4..35 a[h*8+e]
    float* pb = wsf + PART0 + (size_t)(pn * gridDim.x + jc) * PSLOT + grow;
    #pragma unroll
    for (int h = 0; h < 4; h++)
        pb[(size_t)h * 8192] = l[h];
    #pragma unroll
    for (int e = 0; e < 32; e++)
        pb[(size_t)(4 + e) * 8192] = a[e];
}

// ---------- kernel 3a: reduce split-K partials into chunk 0 (per pn) ----------
__global__ __launch_bounds__(256) void k3a_red(float* __restrict__ part, int NCH) {
    int idx = blockIdx.x * 256 + threadIdx.x;   // 147456 float4 slots (2*36*8192/4)
    size_t e = (size_t)idx * 4;
    int pn = (int)(e / PSLOT);
    size_t off = e - (size_t)pn * PSLOT;
    float* base = part + (size_t)pn * NCH * PSLOT + off;
    float4 s = *(const float4*)base;
    for (int c = 1; c < NCH; c++) {
        float4 v = *(const float4*)(base + (size_t)c * PSLOT);
        s.x += v.x; s.y += v.y; s.z += v.z; s.w += v.w;
    }
    *(float4*)base = s;
}

// ---------- kernel 3b: normalize + out-proj + gate (8 rows/block, 32 lanes/row) ----------
__global__ __launch_bounds__(256) void k3b_fin(
    const float* __restrict__ part, int NCH,
    const float* __restrict__ paw, const float* __restrict__ pab,
    const float* __restrict__ naw, const float* __restrict__ nab,
    const float* __restrict__ vpw, const float* __restrict__ vpb,
    const float* __restrict__ vnw, const float* __restrict__ vnb,
    const float* __restrict__ gpw, const float* __restrict__ gpb,
    float* __restrict__ out) {
    __shared__ float sums[8][72];
    __shared__ float Pl[8][64];    // [0..31]=Pp, [32..63]=Pn
    __shared__ float pnv[8][64];   // [0..31]=p,  [32..63]=n
    int tid = threadIdx.x;
    int r = tid >> 5, o = tid & 31;
    int row = blockIdx.x * 8 + r;
    const float* b0 = part + row;                        // pn=0, chunk 0
    const float* b1 = part + (size_t)NCH * PSLOT + row;  // pn=1, chunk 0
    for (int v = o; v < 72; v += 32) {
        int pn = v >= 36;
        int k = v - 36 * pn;
        sums[r][v] = (pn ? b1 : b0)[(size_t)k * 8192];
    }
    __syncthreads();
    // Pp[o] = a_p[o]/l_p[o>>3]; layout: k 0..3 = l, 4..35 = a
    Pl[r][o]      = sums[r][4 + o]  / sums[r][o >> 3];
    Pl[r][32 + o] = sums[r][40 + o] / sums[r][36 + (o >> 3)];
    __syncthreads();
    const float* pw3 = paw + 3*1024; const float* pb3 = pab + 3*32;
    const float* nw3 = naw + 3*1024; const float* nb3 = nab + 3*32;
    float pv = pb3[o], nv = nb3[o];
    #pragma unroll
    for (int d = 0; d < 32; d++) {
        pv += Pl[r][d]      * pw3[o*32 + d];
        nv += Pl[r][32 + d] * nw3[o*32 + d];
    }
    pnv[r][o] = pv; pnv[r][32 + o] = nv;
    __syncthreads();
    float vp = vpb[o], vn = vnb[o], ep = gpb[o], en = gpb[o];
    #pragma unroll
    for (int d = 0; d < 32; d++) {
        float pd = pnv[r][d], nd = pnv[r][32 + d];
        vp += pd * vpw[o*32 + d];
        vn += nd * vnw[o*32 + d];
        ep += pd * gpw[o*32 + d];
        en += nd * gpw[o*32 + d];
    }
    float g = 1.0f / (1.0f + __expf(en - ep));
    out[(size_t)row * 32 + o] = vp * g + vn * (1.0f - g);
}

extern "C" void kernel_launch(void* const* d_in, const int* in_sizes, int n_in,
                              void* d_out, int out_size, void* d_ws, size_t ws_size,
                              hipStream_t stream) {
    const float* feat  = (const float*)d_in[0];
    const float* dmask = (const float*)d_in[1];
    const float* qw  = (const float*)d_in[2];  const float* qb  = (const float*)d_in[3];
    const float* kw  = (const float*)d_in[4];  const float* kb  = (const float*)d_in[5];
    const float* f1w = (const float*)d_in[6];  const float* f1b = (const float*)d_in[7];
    const float* f2w = (const float*)d_in[8];  const float* f2b = (const float*)d_in[9];
    const float* f3w = (const float*)d_in[10]; const float* f3b = (const float*)d_in[11];
    const float* paw = (const float*)d_in[12]; const float* pab = (const float*)d_in[13];
    const float* naw = (const float*)d_in[14]; const float* nab = (const float*)d_in[15];
    const float* vpw = (const float*)d_in[16]; const float* vpb = (const float*)d_in[17];
    const float* vnw = (const float*)d_in[18]; const float* vnb = (const float*)d_in[19];
    const float* gpw = (const float*)d_in[20]; const float* gpb = (const float*)d_in[21];
    float* wsf = (float*)d_ws;
    float* out = (float*)d_out;

    // pick split-K chunk count that fits ws (per chunk: 2 pn x 36*8192 floats)
    size_t avail = ws_size / 4;
    int nch = 1;
    if (avail > (size_t)PART0) {
        size_t per = (size_t)2 * PSLOT;
        size_t m = (avail - PART0) / per;
        nch = (m >= 32) ? 32 : (m >= 16) ? 16 : (m >= 8) ? 8 : (m >= 4) ? 4 :
              (m >= 2) ? 2 : 1;
    }
    int cj = SS / nch;
    float* part = wsf + PART0;

    hipLaunchKernelGGL(k1_proj, dim3(2048), dim3(256), 0, stream,
                       feat, qw, qb, kw, kb, paw, pab, naw, nab, wsf);
    hipLaunchKernelGGL(kA_mask, dim3(8, 32, BB), dim3(256), 0, stream,
                       dmask, wsf, f1w, f1b, f2w, f2b, f3w, f3b);
    hipLaunchKernelGGL(kB_attn, dim3(nch, 8, BB*2), dim3(256), 0, stream,
                       wsf, wsf, cj);
    if (nch > 1)
        hipLaunchKernelGGL(k3a_red, dim3(576), dim3(256), 0, stream, part, nch);
    hipLaunchKernelGGL(k3b_fin, dim3(1024), dim3(256), 0, stream,
                       part, nch, paw, pab, naw, nab, vpw, vpb, vnw, vnb, gpw, gpb,
                       out);
}